// Round 2
// baseline (403.071 us; speedup 1.0000x reference)
//
#include <hip/hip_runtime.h>
#include <hip/hip_bf16.h>

typedef __attribute__((ext_vector_type(8)))  __bf16         bf16x8;
typedef __attribute__((ext_vector_type(4)))  float          f32x4;
typedef __attribute__((ext_vector_type(8)))  unsigned short u16x8;

#define LOG2E 1.44269504088896340736f

#if __has_builtin(__builtin_amdgcn_exp2f)
#define EXP2F(x) __builtin_amdgcn_exp2f(x)
#else
#define EXP2F(x) __builtin_exp2f(x)
#endif

__device__ __forceinline__ unsigned short f2b(float f) {
  union { __bf16 h; unsigned short s; } o; o.h = (__bf16)f; return o.s;
}

// ---------------- kernel 1: h = x@W fp32 (VALU); hT bf16, s1', s2' ----------
// grid 512 x 256 thr; block = 16 rows. W staged in LDS in two 64-row halves.
__global__ __launch_bounds__(256) void k_prep(
    const float* __restrict__ x, const float* __restrict__ W,
    const float* __restrict__ a1, const float* __restrict__ a2,
    const float* __restrict__ ab,
    unsigned short* __restrict__ hT, float* __restrict__ s1p,
    float* __restrict__ s2p) {
  __shared__ __align__(16) float Ws[64 * 128];   // 32 KB (one K-half of W)
  __shared__ __align__(16) float Xs[16 * 128];   // 8 KB
  const int t = threadIdx.x;
  const int rb = blockIdx.x * 16;
  const int r  = t >> 4;    // row 0..15
  const int fg = t & 15;    // feature octet 0..15

  {
    int off = t * 8;
    *(f32x4*)(Xs + off)     = *(const f32x4*)(x + (long)rb * 128 + off);
    *(f32x4*)(Xs + off + 4) = *(const f32x4*)(x + (long)rb * 128 + off + 4);
  }

  float acc[8];
#pragma unroll
  for (int j = 0; j < 8; ++j) acc[j] = 0.f;

  for (int half = 0; half < 2; ++half) {
    __syncthreads();
#pragma unroll
    for (int c = 0; c < 8; ++c) {
      int off = c * 1024 + t * 4;
      *(f32x4*)(Ws + off) = *(const f32x4*)(W + half * 8192 + off);
    }
    __syncthreads();
    for (int k = 0; k < 64; ++k) {
      float xv = Xs[r * 128 + half * 64 + k];
      f32x4 w0 = *(const f32x4*)(Ws + k * 128 + fg * 8);
      f32x4 w1 = *(const f32x4*)(Ws + k * 128 + fg * 8 + 4);
#pragma unroll
      for (int j = 0; j < 4; ++j) {
        acc[j]     += xv * w0[j];
        acc[4 + j] += xv * w1[j];
      }
    }
  }

  float p1 = 0.f, p2 = 0.f;
#pragma unroll
  for (int j = 0; j < 8; ++j) {
    p1 += acc[j] * a1[fg * 8 + j];
    p2 += acc[j] * a2[fg * 8 + j];
  }
#pragma unroll
  for (int mask = 1; mask <= 8; mask <<= 1) {
    p1 += __shfl_xor(p1, mask, 64);
    p2 += __shfl_xor(p2, mask, 64);
  }
  if (fg == 0) {
    s1p[rb + r] = LOG2E * (p1 + ab[0]);   // exp2-domain, bias folded
    s2p[rb + r] = LOG2E * p2;
  }
#pragma unroll
  for (int j = 0; j < 8; ++j)
    hT[(long)(fg * 8 + j) * 8192 + rb + r] = f2b(acc[j]);
}

// ---------------- kernel 2: fused mask+softmax+GEMM, full-K, fp32 out ------
// grid 512 x 256 thr (4 waves). Block = 16 rows x 8192 j x 128 f.
// 2 blocks/CU (145 KB LDS total) so barrier-drain stalls of one block are
// hidden by the other. As/Bs double-buffered -> ONE __syncthreads per K-iter;
// all prefetches issued right after the barrier so the compiler's
// vmcnt(0)-before-s_barrier drain has a full MFMA+store phase to cover it.
__global__ __launch_bounds__(256, 2) void k_attn(
    const float* __restrict__ adj, const unsigned short* __restrict__ hT,
    const float* __restrict__ s1p, const float* __restrict__ s2p,
    float* __restrict__ out) {
  __shared__ __align__(16) unsigned short Bs[2][128 * 128];  // 64 KB dbuf, XOR-swizzled
  __shared__ __align__(16) unsigned short As[2][16 * 136];   // 8.5 KB dbuf, +8 pad/row
  __shared__ float dens[16];

  const int t = threadIdx.x;
  const int i0 = blockIdx.x * 16;
  const int lane = t & 63;
  const int wv = t >> 6;          // 0..3
  const int r  = t >> 4;          // 0..15: adj/As row, Bs staging row
  const int kc = t & 15;          // 0..15: 8-col chunk / staging slot
  const int m    = lane & 15;
  const int quad = lane >> 4;     // 0..3
  const int f0 = wv * 32;         // feature base
  const int cg = kc ^ (r & 7);    // staged global chunk (XOR swizzle; f&7==r&7)

  const float s1v = s1p[i0 + r];
  const float* adjp = adj + (long)(i0 + r) * 8192 + kc * 8;
  const float* s2pp = s2p + kc * 8;
  const unsigned short* hTb = hT + (long)r * 8192 + cg * 8;

  f32x4 acc0, acc1;
#pragma unroll
  for (int p = 0; p < 4; ++p) { acc0[p] = 0.f; acc1[p] = 0.f; }
  float den = 0.f;

  // prologue: iter-0 adj/s2 + hT tile
  f32x4 ar0 = __builtin_nontemporal_load((const f32x4*)(adjp));
  f32x4 ar1 = __builtin_nontemporal_load((const f32x4*)(adjp + 4));
  f32x4 cs0 = *(const f32x4*)(s2pp);
  f32x4 cs1 = *(const f32x4*)(s2pp + 4);
  u16x8 stg[8];
#pragma unroll
  for (int rr = 0; rr < 8; ++rr)
    stg[rr] = *(const u16x8*)(hTb + (long)rr * 131072);   // rr*16 rows * 8192

  for (int it = 0; it < 64; ++it) {
    unsigned short* Bsb = &Bs[it & 1][0];
    unsigned short* Asb = &As[it & 1][0];

    // ---- staged hT regs -> Bs (global chunk cg sits at slot kc) ----
#pragma unroll
    for (int rr = 0; rr < 8; ++rr)
      *(u16x8*)(Bsb + (rr * 16 + r) * 128 + kc * 8) = stg[rr];

    // ---- w = adj * exp2(leaky(t')) for this thread's 8 columns ----
    u16x8 w;
    float dloc = 0.f;
#pragma unroll
    for (int j = 0; j < 4; ++j) {
      float tp = s1v + cs0[j];
      float wval = ar0[j] * EXP2F(fmaxf(tp, 0.2f * tp));
      dloc += wval; w[j] = f2b(wval);
    }
#pragma unroll
    for (int j = 0; j < 4; ++j) {
      float tp = s1v + cs1[j];
      float wval = ar1[j] * EXP2F(fmaxf(tp, 0.2f * tp));
      dloc += wval; w[4 + j] = f2b(wval);
    }
    den += dloc;
    *(u16x8*)(Asb + r * 136 + kc * 8) = w;

    __syncthreads();   // single barrier: As/Bs[buf] visible; buf^1 free to write

    // ---- prefetch next iter (issued right after barrier; latency hides
    // under the MFMA phase + next iter's store/exp2 phase) ----
    const int itn = (it + 1) & 63;
    ar0 = __builtin_nontemporal_load((const f32x4*)(adjp + (long)itn * 128));
    ar1 = __builtin_nontemporal_load((const f32x4*)(adjp + (long)itn * 128 + 4));
    cs0 = *(const f32x4*)(s2pp + itn * 128);
    cs1 = *(const f32x4*)(s2pp + itn * 128 + 4);
    const unsigned short* hTi = hTb + itn * 128;
#pragma unroll
    for (int rr = 0; rr < 8; ++rr)
      stg[rr] = *(const u16x8*)(hTi + (long)rr * 131072);

    // ---- 8x mfma_f32_16x16x32_bf16 (2 feature tiles x 4 K-steps) ----
#pragma unroll
    for (int ks = 0; ks < 4; ++ks) {
      bf16x8 af = *(const bf16x8*)(Asb + m * 136 + ks * 32 + quad * 8);
      int slot = (ks * 4 + quad) ^ (m & 7);
      {
        bf16x8 bv = *(const bf16x8*)(Bsb + (f0 + m) * 128 + slot * 8);
        acc0 = __builtin_amdgcn_mfma_f32_16x16x32_bf16(af, bv, acc0, 0, 0, 0);
      }
      {
        bf16x8 bv = *(const bf16x8*)(Bsb + (f0 + 16 + m) * 128 + slot * 8);
        acc1 = __builtin_amdgcn_mfma_f32_16x16x32_bf16(af, bv, acc1, 0, 0, 0);
      }
    }
    // no trailing barrier: next iter writes the other buffer; the barrier at
    // it+1 orders those writes after everyone's reads of this buffer.
  }

  // ---- full-row denominator: reduce over kc (lane low4), share via LDS ----
  den += __shfl_xor(den, 1, 64);
  den += __shfl_xor(den, 2, 64);
  den += __shfl_xor(den, 4, 64);
  den += __shfl_xor(den, 8, 64);
  if (kc == 0) dens[r] = den;
  __syncthreads();

  // ---- divide + fp32 store. C layout (16x16): col=lane&15, row=quad*4+reg --
#pragma unroll
  for (int p = 0; p < 4; ++p) {
    int row = quad * 4 + p;
    float d = dens[row];
    float inv = (d != 0.f) ? (1.f / d) : 0.f;
    out[(long)(i0 + row) * 128 + f0 + m]      = acc0[p] * inv;
    out[(long)(i0 + row) * 128 + f0 + 16 + m] = acc1[p] * inv;
  }
}

extern "C" void kernel_launch(void* const* d_in, const int* in_sizes, int n_in,
                              void* d_out, int out_size, void* d_ws, size_t ws_size,
                              hipStream_t stream) {
  // size-based input dispatch (a1/a2 keep their relative order)
  int ix = 0, iadj = 1, iw = 2, ia1 = 3, ia2 = 4, iab = 5;
  {
    int f128[2] = {-1, -1};
    int tx = -1, tadj = -1, tw = -1, tab = -1, n128 = 0;
    for (int i = 0; i < n_in; ++i) {
      int s = in_sizes[i];
      if (s == 67108864) tadj = i;
      else if (s == 1048576) tx = i;
      else if (s == 16384) tw = i;
      else if (s == 128 && n128 < 2) f128[n128++] = i;
      else if (s == 1) tab = i;
    }
    if (tx >= 0 && tadj >= 0 && tw >= 0 && tab >= 0 && n128 == 2) {
      ix = tx; iadj = tadj; iw = tw; ia1 = f128[0]; ia2 = f128[1]; iab = tab;
    }
  }
  const float* x   = (const float*)d_in[ix];
  const float* adj = (const float*)d_in[iadj];
  const float* W   = (const float*)d_in[iw];
  const float* a1  = (const float*)d_in[ia1];
  const float* a2  = (const float*)d_in[ia2];
  const float* ab  = (const float*)d_in[iab];

  char* ws = (char*)d_ws;
  unsigned short* hT = (unsigned short*)(ws);           // 2 MB  bf16 h^T [128][8192]
  float* s1p = (float*)(ws + 2097152);                  // 32 KB
  float* s2p = (float*)(ws + 2097152 + 32768);          // 32 KB

  k_prep<<<dim3(512), dim3(256), 0, stream>>>(x, W, a1, a2, ab, hT, s1p, s2p);
  k_attn<<<dim3(512), dim3(256), 0, stream>>>(adj, hT, s1p, s2p, (float*)d_out);
}

// Round 3
// 398.242 us; speedup vs baseline: 1.0121x; 1.0121x over previous
//
#include <hip/hip_runtime.h>
#include <hip/hip_bf16.h>

typedef __attribute__((ext_vector_type(8)))  __bf16         bf16x8;
typedef __attribute__((ext_vector_type(4)))  float          f32x4;
typedef __attribute__((ext_vector_type(8)))  unsigned short u16x8;

#define LOG2E 1.44269504088896340736f

#if __has_builtin(__builtin_amdgcn_exp2f)
#define EXP2F(x) __builtin_amdgcn_exp2f(x)
#else
#define EXP2F(x) __builtin_exp2f(x)
#endif

__device__ __forceinline__ unsigned short f2b(float f) {
  union { __bf16 h; unsigned short s; } o; o.h = (__bf16)f; return o.s;
}

// ---------------- kernel 1: h = x@W fp32 (VALU); hT bf16, s1', s2' ----------
// grid 512 x 256 thr; block = 16 rows. W staged in LDS in two 64-row halves.
__global__ __launch_bounds__(256) void k_prep(
    const float* __restrict__ x, const float* __restrict__ W,
    const float* __restrict__ a1, const float* __restrict__ a2,
    const float* __restrict__ ab,
    unsigned short* __restrict__ hT, float* __restrict__ s1p,
    float* __restrict__ s2p) {
  __shared__ __align__(16) float Ws[64 * 128];   // 32 KB (one K-half of W)
  __shared__ __align__(16) float Xs[16 * 128];   // 8 KB
  const int t = threadIdx.x;
  const int rb = blockIdx.x * 16;
  const int r  = t >> 4;    // row 0..15
  const int fg = t & 15;    // feature octet 0..15

  {
    int off = t * 8;
    *(f32x4*)(Xs + off)     = *(const f32x4*)(x + (long)rb * 128 + off);
    *(f32x4*)(Xs + off + 4) = *(const f32x4*)(x + (long)rb * 128 + off + 4);
  }

  float acc[8];
#pragma unroll
  for (int j = 0; j < 8; ++j) acc[j] = 0.f;

  for (int half = 0; half < 2; ++half) {
    __syncthreads();
#pragma unroll
    for (int c = 0; c < 8; ++c) {
      int off = c * 1024 + t * 4;
      *(f32x4*)(Ws + off) = *(const f32x4*)(W + half * 8192 + off);
    }
    __syncthreads();
    for (int k = 0; k < 64; ++k) {
      float xv = Xs[r * 128 + half * 64 + k];
      f32x4 w0 = *(const f32x4*)(Ws + k * 128 + fg * 8);
      f32x4 w1 = *(const f32x4*)(Ws + k * 128 + fg * 8 + 4);
#pragma unroll
      for (int j = 0; j < 4; ++j) {
        acc[j]     += xv * w0[j];
        acc[4 + j] += xv * w1[j];
      }
    }
  }

  float p1 = 0.f, p2 = 0.f;
#pragma unroll
  for (int j = 0; j < 8; ++j) {
    p1 += acc[j] * a1[fg * 8 + j];
    p2 += acc[j] * a2[fg * 8 + j];
  }
#pragma unroll
  for (int mask = 1; mask <= 8; mask <<= 1) {
    p1 += __shfl_xor(p1, mask, 64);
    p2 += __shfl_xor(p2, mask, 64);
  }
  if (fg == 0) {
    s1p[rb + r] = LOG2E * (p1 + ab[0]);   // exp2-domain, bias folded
    s2p[rb + r] = LOG2E * p2;
  }
#pragma unroll
  for (int j = 0; j < 8; ++j)
    hT[(long)(fg * 8 + j) * 8192 + rb + r] = f2b(acc[j]);
}

// ---------------- kernel 2: fused mask+softmax+GEMM, full-K, fp32 out ------
// grid 256 x 512 thr (8 waves, 1 block/CU). Block = 32 rows x 8192 j x 128 f.
// Geometry identical to the 389µs r0 kernel (keeps hT staging at 32 KB/iter/CU
// — the r1 16-row/2-block variant doubled that and regressed 13 µs).
// Schedule change only: As/Bs double-buffered -> ONE __syncthreads per iter,
// and ALL global prefetches (adj, s2, hT) issued immediately AFTER the
// barrier so the compiler's vmcnt(0)-before-s_barrier drain at the NEXT
// barrier has a full iteration (~1000+ cy) of cover for the ~900 cy HBM load.
__global__ __launch_bounds__(512, 1) void k_attn(
    const float* __restrict__ adj, const unsigned short* __restrict__ hT,
    const float* __restrict__ s1p, const float* __restrict__ s2p,
    float* __restrict__ out) {
  __shared__ __align__(16) unsigned short Bs[2][128 * 128];  // 64 KB dbuf, XOR-swizzled
  __shared__ __align__(16) unsigned short As[2][32 * 136];   // 17 KB dbuf, +8 pad/row
  __shared__ float dens[32];

  const int t = threadIdx.x;
  const int i0 = blockIdx.x * 32;
  const int lane = t & 63;
  const int wv = t >> 6;          // 0..7
  const int r  = t >> 4;          // 0..31: adj/As row, Bs staging row-group
  const int kc = t & 15;          // 0..15: 8-col chunk / staging slot
  const int m    = lane & 15;
  const int quad = lane >> 4;     // 0..3
  const int rt = wv & 1;          // row tile
  const int f0 = (wv >> 1) * 32;  // feature base
  const int cg = kc ^ (r & 7);    // staged global chunk (XOR swizzle; f&7==r&7)

  const float s1v = s1p[i0 + r];
  const float* adjp = adj + (long)(i0 + r) * 8192 + kc * 8;
  const float* s2pp = s2p + kc * 8;
  const unsigned short* hTb = hT + (long)r * 8192 + cg * 8;

  f32x4 acc0, acc1;
#pragma unroll
  for (int p = 0; p < 4; ++p) { acc0[p] = 0.f; acc1[p] = 0.f; }
  float den = 0.f;

  // prologue: iter-0 adj/s2 + hT tile
  f32x4 ar0 = __builtin_nontemporal_load((const f32x4*)(adjp));
  f32x4 ar1 = __builtin_nontemporal_load((const f32x4*)(adjp + 4));
  f32x4 cs0 = *(const f32x4*)(s2pp);
  f32x4 cs1 = *(const f32x4*)(s2pp + 4);
  u16x8 stg[4];
#pragma unroll
  for (int rr = 0; rr < 4; ++rr)
    stg[rr] = *(const u16x8*)(hTb + (long)rr * 262144);   // rr*32 rows * 8192

  for (int it = 0; it < 64; ++it) {
    unsigned short* Bsb = &Bs[it & 1][0];
    unsigned short* Asb = &As[it & 1][0];

    // ---- staged hT regs -> Bs (global chunk cg sits at slot kc) ----
#pragma unroll
    for (int rr = 0; rr < 4; ++rr)
      *(u16x8*)(Bsb + (rr * 32 + r) * 128 + kc * 8) = stg[rr];

    // ---- w = adj * exp2(leaky(t')) for this thread's 8 columns ----
    u16x8 w;
    float dloc = 0.f;
#pragma unroll
    for (int j = 0; j < 4; ++j) {
      float tp = s1v + cs0[j];
      float wval = ar0[j] * EXP2F(fmaxf(tp, 0.2f * tp));
      dloc += wval; w[j] = f2b(wval);
    }
#pragma unroll
    for (int j = 0; j < 4; ++j) {
      float tp = s1v + cs1[j];
      float wval = ar1[j] * EXP2F(fmaxf(tp, 0.2f * tp));
      dloc += wval; w[4 + j] = f2b(wval);
    }
    den += dloc;
    *(u16x8*)(Asb + r * 136 + kc * 8) = w;

    __syncthreads();   // single barrier: As/Bs[buf] visible; buf^1 free to write

    // ---- prefetch next iter (issued right after barrier; full iteration of
    // MFMA + next stores/exp2 covers the HBM/L2 latency before next drain) ----
    const int itn = (it + 1) & 63;
    ar0 = __builtin_nontemporal_load((const f32x4*)(adjp + (long)itn * 128));
    ar1 = __builtin_nontemporal_load((const f32x4*)(adjp + (long)itn * 128 + 4));
    cs0 = *(const f32x4*)(s2pp + itn * 128);
    cs1 = *(const f32x4*)(s2pp + itn * 128 + 4);
    const unsigned short* hTi = hTb + itn * 128;
#pragma unroll
    for (int rr = 0; rr < 4; ++rr)
      stg[rr] = *(const u16x8*)(hTi + (long)rr * 262144);

    // ---- 8x mfma_f32_16x16x32_bf16 (2 feature tiles x 4 K-steps) ----
#pragma unroll
    for (int ks = 0; ks < 4; ++ks) {
      bf16x8 af = *(const bf16x8*)(Asb + (rt * 16 + m) * 136 + ks * 32 + quad * 8);
      int slot = (ks * 4 + quad) ^ (m & 7);
      {
        bf16x8 bv = *(const bf16x8*)(Bsb + (f0 + m) * 128 + slot * 8);
        acc0 = __builtin_amdgcn_mfma_f32_16x16x32_bf16(af, bv, acc0, 0, 0, 0);
      }
      {
        bf16x8 bv = *(const bf16x8*)(Bsb + (f0 + 16 + m) * 128 + slot * 8);
        acc1 = __builtin_amdgcn_mfma_f32_16x16x32_bf16(af, bv, acc1, 0, 0, 0);
      }
    }
    // no trailing barrier: next iter writes the other buffer; the barrier at
    // it+1 orders those writes after everyone's reads of this buffer.
  }

  // ---- full-row denominator: reduce over kc (lane low4), share via LDS ----
  den += __shfl_xor(den, 1, 64);
  den += __shfl_xor(den, 2, 64);
  den += __shfl_xor(den, 4, 64);
  den += __shfl_xor(den, 8, 64);
  if (kc == 0) dens[r] = den;
  __syncthreads();

  // ---- divide + fp32 store. C layout (16x16): col=lane&15, row=quad*4+reg --
#pragma unroll
  for (int p = 0; p < 4; ++p) {
    int row = rt * 16 + quad * 4 + p;
    float d = dens[row];
    float inv = (d != 0.f) ? (1.f / d) : 0.f;
    out[(long)(i0 + row) * 128 + f0 + m]      = acc0[p] * inv;
    out[(long)(i0 + row) * 128 + f0 + 16 + m] = acc1[p] * inv;
  }
}

extern "C" void kernel_launch(void* const* d_in, const int* in_sizes, int n_in,
                              void* d_out, int out_size, void* d_ws, size_t ws_size,
                              hipStream_t stream) {
  // size-based input dispatch (a1/a2 keep their relative order)
  int ix = 0, iadj = 1, iw = 2, ia1 = 3, ia2 = 4, iab = 5;
  {
    int f128[2] = {-1, -1};
    int tx = -1, tadj = -1, tw = -1, tab = -1, n128 = 0;
    for (int i = 0; i < n_in; ++i) {
      int s = in_sizes[i];
      if (s == 67108864) tadj = i;
      else if (s == 1048576) tx = i;
      else if (s == 16384) tw = i;
      else if (s == 128 && n128 < 2) f128[n128++] = i;
      else if (s == 1) tab = i;
    }
    if (tx >= 0 && tadj >= 0 && tw >= 0 && tab >= 0 && n128 == 2) {
      ix = tx; iadj = tadj; iw = tw; ia1 = f128[0]; ia2 = f128[1]; iab = tab;
    }
  }
  const float* x   = (const float*)d_in[ix];
  const float* adj = (const float*)d_in[iadj];
  const float* W   = (const float*)d_in[iw];
  const float* a1  = (const float*)d_in[ia1];
  const float* a2  = (const float*)d_in[ia2];
  const float* ab  = (const float*)d_in[iab];

  char* ws = (char*)d_ws;
  unsigned short* hT = (unsigned short*)(ws);           // 2 MB  bf16 h^T [128][8192]
  float* s1p = (float*)(ws + 2097152);                  // 32 KB
  float* s2p = (float*)(ws + 2097152 + 32768);          // 32 KB

  k_prep<<<dim3(512), dim3(256), 0, stream>>>(x, W, a1, a2, ab, hT, s1p, s2p);
  k_attn<<<dim3(256), dim3(512), 0, stream>>>(adj, hT, s1p, s2p, (float*)d_out);
}

// Round 4
// 390.669 us; speedup vs baseline: 1.0317x; 1.0194x over previous
//
#include <hip/hip_runtime.h>
#include <hip/hip_bf16.h>

typedef __attribute__((ext_vector_type(8)))  __bf16         bf16x8;
typedef __attribute__((ext_vector_type(4)))  float          f32x4;
typedef __attribute__((ext_vector_type(8)))  unsigned short u16x8;

#define LOG2E 1.44269504088896340736f

#if __has_builtin(__builtin_amdgcn_exp2f)
#define EXP2F(x) __builtin_amdgcn_exp2f(x)
#else
#define EXP2F(x) __builtin_exp2f(x)
#endif

__device__ __forceinline__ unsigned short f2b(float f) {
  union { __bf16 h; unsigned short s; } o; o.h = (__bf16)f; return o.s;
}

// ---------------- kernel 1: h = x@W fp32 (VALU); hT bf16, s1', s2' ----------
// grid 512 x 256 thr; block = 16 rows. W staged in LDS in two 64-row halves.
__global__ __launch_bounds__(256) void k_prep(
    const float* __restrict__ x, const float* __restrict__ W,
    const float* __restrict__ a1, const float* __restrict__ a2,
    const float* __restrict__ ab,
    unsigned short* __restrict__ hT, float* __restrict__ s1p,
    float* __restrict__ s2p) {
  __shared__ __align__(16) float Ws[64 * 128];   // 32 KB (one K-half of W)
  __shared__ __align__(16) float Xs[16 * 128];   // 8 KB
  const int t = threadIdx.x;
  const int rb = blockIdx.x * 16;
  const int r  = t >> 4;    // row 0..15
  const int fg = t & 15;    // feature octet 0..15

  {
    int off = t * 8;
    *(f32x4*)(Xs + off)     = *(const f32x4*)(x + (long)rb * 128 + off);
    *(f32x4*)(Xs + off + 4) = *(const f32x4*)(x + (long)rb * 128 + off + 4);
  }

  float acc[8];
#pragma unroll
  for (int j = 0; j < 8; ++j) acc[j] = 0.f;

  for (int half = 0; half < 2; ++half) {
    __syncthreads();
#pragma unroll
    for (int c = 0; c < 8; ++c) {
      int off = c * 1024 + t * 4;
      *(f32x4*)(Ws + off) = *(const f32x4*)(W + half * 8192 + off);
    }
    __syncthreads();
    for (int k = 0; k < 64; ++k) {
      float xv = Xs[r * 128 + half * 64 + k];
      f32x4 w0 = *(const f32x4*)(Ws + k * 128 + fg * 8);
      f32x4 w1 = *(const f32x4*)(Ws + k * 128 + fg * 8 + 4);
#pragma unroll
      for (int j = 0; j < 4; ++j) {
        acc[j]     += xv * w0[j];
        acc[4 + j] += xv * w1[j];
      }
    }
  }

  float p1 = 0.f, p2 = 0.f;
#pragma unroll
  for (int j = 0; j < 8; ++j) {
    p1 += acc[j] * a1[fg * 8 + j];
    p2 += acc[j] * a2[fg * 8 + j];
  }
#pragma unroll
  for (int mask = 1; mask <= 8; mask <<= 1) {
    p1 += __shfl_xor(p1, mask, 64);
    p2 += __shfl_xor(p2, mask, 64);
  }
  if (fg == 0) {
    s1p[rb + r] = LOG2E * (p1 + ab[0]);   // exp2-domain, bias folded
    s2p[rb + r] = LOG2E * p2;
  }
#pragma unroll
  for (int j = 0; j < 8; ++j)
    hT[(long)(fg * 8 + j) * 8192 + rb + r] = f2b(acc[j]);
}

// ---------------- kernel 2: fused mask+softmax+GEMM, split-j partials ------
// grid 512 = 256 row-blocks x 2 column-halves; 512 thr (8 waves).
// Inner loop is BIT-IDENTICAL to the best-measured r0 schedule (two barriers,
// single-buffer As/Bs); only 32 iterations over a 4096-col half.
// 40.8 KB LDS + <=128 VGPR -> 2 blocks/CU co-resident, so one block's
// barrier/drain stalls are covered by the other block's waves, with per-CU
// hT staging traffic UNCHANGED vs r0 (the r1 lesson).
__global__ __launch_bounds__(512, 4) void k_attn(
    const float* __restrict__ adj, const unsigned short* __restrict__ hT,
    const float* __restrict__ s1p, const float* __restrict__ s2p,
    float* __restrict__ pout, float* __restrict__ pden) {
  __shared__ __align__(16) unsigned short Bs[128 * 128];  // hT k-tile, XOR-swizzled
  __shared__ __align__(16) unsigned short As[32 * 136];   // w tile, +8 pad/row

  const int t = threadIdx.x;
  const int i0 = (blockIdx.x >> 1) * 32;
  const int jh = blockIdx.x & 1;          // column half
  const long jbase = (long)jh * 4096;
  const int lane = t & 63;
  const int wv = t >> 6;          // 0..7
  const int r  = t >> 4;          // 0..31: adj/As row, Bs staging row-group
  const int kc = t & 15;          // 0..15: 8-col chunk / staging slot
  const int m    = lane & 15;
  const int quad = lane >> 4;     // 0..3
  const int rt = wv & 1;          // row tile
  const int f0 = (wv >> 1) * 32;  // feature base

  const float s1v = s1p[i0 + r];
  const float* adjp = adj + (long)(i0 + r) * 8192 + jbase + kc * 8;
  const float* s2pp = s2p + jbase + kc * 8;

  f32x4 acc0, acc1;
#pragma unroll
  for (int p = 0; p < 4; ++p) { acc0[p] = 0.f; acc1[p] = 0.f; }
  float den = 0.f;

  // prologue: iter-0 adj/s2 + hT tile
  f32x4 ar0 = __builtin_nontemporal_load((const f32x4*)(adjp));
  f32x4 ar1 = __builtin_nontemporal_load((const f32x4*)(adjp + 4));
  f32x4 cs0 = *(const f32x4*)(s2pp);
  f32x4 cs1 = *(const f32x4*)(s2pp + 4);
  u16x8 stg[4];
#pragma unroll
  for (int rr = 0; rr < 4; ++rr) {
    int f = rr * 32 + r;
    int cg = kc ^ (f & 7);
    stg[rr] = *(const u16x8*)(hT + (long)f * 8192 + jbase + cg * 8);
  }

  for (int it = 0; it < 32; ++it) {
    // ---- staged hT regs -> Bs (global chunk cg sits at slot kc) ----
#pragma unroll
    for (int rr = 0; rr < 4; ++rr) {
      int f = rr * 32 + r;
      *(u16x8*)(Bs + f * 128 + kc * 8) = stg[rr];
    }
    // ---- prefetch next adj/s2 ----
    const int itn = (it + 1) & 31;
    f32x4 nr0 = __builtin_nontemporal_load((const f32x4*)(adjp + (long)itn * 128));
    f32x4 nr1 = __builtin_nontemporal_load((const f32x4*)(adjp + (long)itn * 128 + 4));
    f32x4 ns0 = *(const f32x4*)(s2pp + itn * 128);
    f32x4 ns1 = *(const f32x4*)(s2pp + itn * 128 + 4);

    // ---- w = adj * exp2(leaky(t')) for this thread's 8 columns ----
    u16x8 w;
    float dloc = 0.f;
#pragma unroll
    for (int j = 0; j < 4; ++j) {
      float tp = s1v + cs0[j];
      float wval = ar0[j] * EXP2F(fmaxf(tp, 0.2f * tp));
      dloc += wval; w[j] = f2b(wval);
    }
#pragma unroll
    for (int j = 0; j < 4; ++j) {
      float tp = s1v + cs1[j];
      float wval = ar1[j] * EXP2F(fmaxf(tp, 0.2f * tp));
      dloc += wval; w[4 + j] = f2b(wval);
    }
    den += dloc;
    *(u16x8*)(As + r * 136 + kc * 8) = w;

    __syncthreads();   // As/Bs visible to all waves

    // ---- prefetch next hT tile (latency hides under MFMA) ----
    if (it < 31) {
      const unsigned short* hTi = hT + jbase + (long)(it + 1) * 128;
#pragma unroll
      for (int rr = 0; rr < 4; ++rr) {
        int f = rr * 32 + r;
        int cg = kc ^ (f & 7);
        stg[rr] = *(const u16x8*)(hTi + (long)f * 8192 + cg * 8);
      }
    }

    // ---- 8x mfma_f32_16x16x32_bf16 (2 feature tiles x 4 K-steps) ----
#pragma unroll
    for (int ks = 0; ks < 4; ++ks) {
      bf16x8 af = *(const bf16x8*)(As + (rt * 16 + m) * 136 + ks * 32 + quad * 8);
      int c = ks * 4 + quad;
      {
        int f = f0 + m;
        int slot = c ^ (f & 7);
        bf16x8 bv = *(const bf16x8*)(Bs + f * 128 + slot * 8);
        acc0 = __builtin_amdgcn_mfma_f32_16x16x32_bf16(af, bv, acc0, 0, 0, 0);
      }
      {
        int f = f0 + 16 + m;
        int slot = c ^ (f & 7);
        bf16x8 bv = *(const bf16x8*)(Bs + f * 128 + slot * 8);
        acc1 = __builtin_amdgcn_mfma_f32_16x16x32_bf16(af, bv, acc1, 0, 0, 0);
      }
    }
    __syncthreads();   // reads done before next iter's stores

    ar0 = nr0; ar1 = nr1; cs0 = ns0; cs1 = ns1;
  }

  // ---- partial denominator: reduce over kc (lane low4) ----
  den += __shfl_xor(den, 1, 64);
  den += __shfl_xor(den, 2, 64);
  den += __shfl_xor(den, 4, 64);
  den += __shfl_xor(den, 8, 64);
  if (kc == 0) pden[jh * 8192 + i0 + r] = den;

  // ---- partial numerator store (no divide). C layout: col=lane&15, row=quad*4+reg
  float* po = pout + (long)jh * 1048576;   // 8192*128 plane
#pragma unroll
  for (int p = 0; p < 4; ++p) {
    int row = rt * 16 + quad * 4 + p;
    po[(long)(i0 + row) * 128 + f0 + m]      = acc0[p];
    po[(long)(i0 + row) * 128 + f0 + 16 + m] = acc1[p];
  }
}

// ---------------- kernel 3: combine halves: out = (pA+pB)/(dA+dB) ----------
__global__ __launch_bounds__(256) void k_comb(
    const float* __restrict__ pout, const float* __restrict__ pden,
    float* __restrict__ out) {
  int g = blockIdx.x * 256 + threadIdx.x;   // f32x4 index, 0..262143
  int i = g >> 5;                           // row (32 f32x4 per 128-f row)
  f32x4 a = *(const f32x4*)(pout + (long)g * 4);
  f32x4 b = *(const f32x4*)(pout + 1048576 + (long)g * 4);
  float d = pden[i] + pden[8192 + i];
  float inv = (d != 0.f) ? (1.f / d) : 0.f;
  f32x4 o;
#pragma unroll
  for (int p = 0; p < 4; ++p) o[p] = (a[p] + b[p]) * inv;
  *(f32x4*)(out + (long)g * 4) = o;
}

extern "C" void kernel_launch(void* const* d_in, const int* in_sizes, int n_in,
                              void* d_out, int out_size, void* d_ws, size_t ws_size,
                              hipStream_t stream) {
  // size-based input dispatch (a1/a2 keep their relative order)
  int ix = 0, iadj = 1, iw = 2, ia1 = 3, ia2 = 4, iab = 5;
  {
    int f128[2] = {-1, -1};
    int tx = -1, tadj = -1, tw = -1, tab = -1, n128 = 0;
    for (int i = 0; i < n_in; ++i) {
      int s = in_sizes[i];
      if (s == 67108864) tadj = i;
      else if (s == 1048576) tx = i;
      else if (s == 16384) tw = i;
      else if (s == 128 && n128 < 2) f128[n128++] = i;
      else if (s == 1) tab = i;
    }
    if (tx >= 0 && tadj >= 0 && tw >= 0 && tab >= 0 && n128 == 2) {
      ix = tx; iadj = tadj; iw = tw; ia1 = f128[0]; ia2 = f128[1]; iab = tab;
    }
  }
  const float* x   = (const float*)d_in[ix];
  const float* adj = (const float*)d_in[iadj];
  const float* W   = (const float*)d_in[iw];
  const float* a1  = (const float*)d_in[ia1];
  const float* a2  = (const float*)d_in[ia2];
  const float* ab  = (const float*)d_in[iab];

  char* ws = (char*)d_ws;
  unsigned short* hT = (unsigned short*)(ws);           // 2 MB  bf16 h^T [128][8192]
  float* s1p  = (float*)(ws + 2097152);                 // 32 KB
  float* s2p  = (float*)(ws + 2097152 + 32768);         // 32 KB
  float* pout = (float*)(ws + 2162688);                 // 8 MB  [2][8192][128]
  float* pden = (float*)(ws + 2162688 + 8388608);       // 64 KB [2][8192]

  k_prep<<<dim3(512), dim3(256), 0, stream>>>(x, W, a1, a2, ab, hT, s1p, s2p);
  k_attn<<<dim3(512), dim3(512), 0, stream>>>(adj, hT, s1p, s2p, pout, pden);
  k_comb<<<dim3(1024), dim3(256), 0, stream>>>(pout, pden, (float*)d_out);
}